// Round 1
// baseline (517.992 us; speedup 1.0000x reference)
//
#include <hip/hip_runtime.h>

// ProposalLayer for Faster R-CNN RPN on MI355X.
// B=4, H=64, W=96, A=9 anchors, N=55296 anchors/image.
// TEST cfg: pre=6000, post=300, thresh=0.7, min_size=16.

#define NB 4
#define AH 64
#define AW 96
#define NA 9
#define NPC (AH*AW*NA)      // 55296
#define CAP 16384           // candidate buffer per image
#define PREMAX 12000        // max 'pre' (TRAIN)
#define POSTMAX 2048        // max 'post' (TRAIN)
#define NBUCK 4096

// anchors from _generate_anchors(16, (0.5,1,2), (8,16,32)) — verified vs numpy
__constant__ float c_anchors[NA][4] = {
  { -84.f,  -40.f,  99.f,  55.f},
  {-176.f,  -88.f, 191.f, 103.f},
  {-360.f, -184.f, 375.f, 199.f},
  { -56.f,  -56.f,  71.f,  71.f},
  {-120.f, -120.f, 135.f, 135.f},
  {-248.f, -248.f, 263.f, 263.f},
  { -36.f,  -80.f,  51.f,  95.f},
  { -80.f, -168.f,  95.f, 183.f},
  {-168.f, -344.f, 183.f, 359.f},
};

// static scratch (avoids depending on ws_size); rewritten deterministically each call
__device__ unsigned int          g_keys[NB][NPC];
__device__ float4                g_boxes[NB][NPC];
__device__ unsigned int          g_hist[NB][NBUCK];
__device__ unsigned int          g_pivot[NB];
__device__ int                   g_cnt[NB];
__device__ unsigned long long    g_cand[NB][CAP];
__device__ float4                g_sbox[NB][PREMAX];

__global__ void k_init() {
  int t = blockIdx.x * blockDim.x + threadIdx.x;
  if (t < NB * NBUCK) ((unsigned int*)g_hist)[t] = 0u;
  if (t < NB) g_cnt[t] = 0;
}

__global__ void k_decode(const float* __restrict__ cls,
                         const float* __restrict__ dlt,
                         const float* __restrict__ ish) {
#pragma clang fp contract(off)
  int b = blockIdx.y;
  int i = blockIdx.x * blockDim.x + threadIdx.x;
  __shared__ unsigned int lh[NBUCK];
  for (int t = threadIdx.x; t < NBUCK; t += blockDim.x) lh[t] = 0u;
  __syncthreads();

  if (i < NPC) {
    int a   = i % NA;
    int pos = i / NA;
    int wx  = pos % AW;
    int hy  = pos / AW;

    float score = cls[((b * (2*NA) + NA + a) * AH + hy) * AW + wx];
    int dbase = ((b * (4*NA) + a*4) * AH + hy) * AW + wx;
    const int hw = AH * AW;
    float d0 = dlt[dbase];
    float d1 = dlt[dbase + hw];
    float d2 = dlt[dbase + 2*hw];
    float d3 = dlt[dbase + 3*hw];

    float shx = (float)(wx * 16);
    float shy = (float)(hy * 16);
    float ax1 = c_anchors[a][0] + shx;
    float ay1 = c_anchors[a][1] + shy;
    float ax2 = c_anchors[a][2] + shx;
    float ay2 = c_anchors[a][3] + shy;

    float aw_ = ax2 - ax1 + 1.0f;
    float ah_ = ay2 - ay1 + 1.0f;
    float acx = ax1 + 0.5f * aw_;
    float acy = ay1 + 0.5f * ah_;

    float pcx = d0 * aw_ + acx;
    float pcy = d1 * ah_ + acy;
    float pw  = expf(d2) * aw_;
    float ph  = expf(d3) * ah_;

    float x1 = pcx - 0.5f * pw;
    float y1 = pcy - 0.5f * ph;
    float x2 = pcx + 0.5f * pw;
    float y2 = pcy + 0.5f * ph;

    float imh = ish[b*2 + 0];
    float imw = ish[b*2 + 1];
    x1 = fminf(fmaxf(x1, 0.0f), imw - 1.0f);
    x2 = fminf(fmaxf(x2, 0.0f), imw - 1.0f);
    y1 = fminf(fmaxf(y1, 0.0f), imh - 1.0f);
    y2 = fminf(fmaxf(y2, 0.0f), imh - 1.0f);

    bool valid = ((x2 - x1 + 1.0f) >= 16.0f) && ((y2 - y1 + 1.0f) >= 16.0f);

    g_boxes[b][i] = make_float4(x1, y1, x2, y2);

    unsigned int key = 0u;
    if (valid) {
      unsigned int ub = __float_as_uint(score);
      key = (ub >> 31) ? ~ub : (ub | 0x80000000u);  // monotonic flip; valid keys >= 0x00800000
    }
    g_keys[b][i] = key;
    atomicAdd(&lh[key >> 20], 1u);
  }
  __syncthreads();
  for (int t = threadIdx.x; t < NBUCK; t += blockDim.x)
    if (lh[t]) atomicAdd(&g_hist[b][t], lh[t]);
}

// per-image: find max bucket P>=1 with suffix-count(P) >= pre
__global__ void k_pivot(const int* __restrict__ train) {
  int b = blockIdx.x;
  int tid = threadIdx.x;  // 256
  unsigned int pre = train[0] ? 12000u : 6000u;
  __shared__ unsigned int h[NBUCK];
  __shared__ unsigned int csum[256];
  __shared__ unsigned int csuf[257];
  __shared__ int best;
  for (int t = tid; t < NBUCK; t += 256) h[t] = g_hist[b][t];
  if (tid == 0) best = 0;
  __syncthreads();
  unsigned int s = 0;
  for (int q = 0; q < 16; ++q) s += h[tid*16 + q];
  csum[tid] = s;
  __syncthreads();
  if (tid == 0) {
    unsigned int run = 0;
    csuf[256] = 0;
    for (int c = 255; c >= 0; --c) { run += csum[c]; csuf[c] = run; }
  }
  __syncthreads();
  unsigned int run = csuf[tid + 1];
  int loc = 0;
  for (int q = tid*16 + 15; q >= tid*16; --q) {
    run += h[q];
    if (run >= pre && q >= 1) { loc = q; break; }  // highest q in this chunk with S(q)>=pre
  }
  if (loc) atomicMax(&best, loc);
  __syncthreads();
  if (tid == 0) g_pivot[b] = ((unsigned int)max(best, 1)) << 20;
}

__global__ void k_compact() {
  int b = blockIdx.y;
  int i = blockIdx.x * blockDim.x + threadIdx.x;
  if (i >= NPC) return;
  unsigned int key = g_keys[b][i];
  if (key != 0u && key >= g_pivot[b]) {
    int pos = atomicAdd(&g_cnt[b], 1);
    if (pos < CAP)
      g_cand[b][pos] = ((unsigned long long)key << 32) |
                       (unsigned long long)(0xFFFFFFFFu - (unsigned int)i);
  }
}

// exact rank of each candidate (descending key, ascending index) -> scatter sorted boxes
__global__ void k_rank(const int* __restrict__ train) {
  int b = blockIdx.y;
  int j = blockIdx.x * blockDim.x + threadIdx.x;
  int pre = train[0] ? 12000 : 6000;
  int Cb = g_cnt[b]; if (Cb > CAP) Cb = CAP;
  if (j >= Cb) return;
  unsigned long long cj = g_cand[b][j];
  int rank = 0;
  const unsigned long long* cb = &g_cand[b][0];
#pragma unroll 8
  for (int k = 0; k < Cb; ++k) rank += (cb[k] > cj) ? 1 : 0;
  if (rank < pre) {
    unsigned int idx = 0xFFFFFFFFu - (unsigned int)(cj & 0xFFFFFFFFull);
    g_sbox[b][rank] = g_boxes[b][idx];
  }
}

// one wave per image: sequential greedy NMS with kept boxes in LDS, early exit at 'post' keeps
__global__ void k_nms(float* __restrict__ out, const int* __restrict__ train, int post) {
#pragma clang fp contract(off)
  int b = blockIdx.x;
  int lane = threadIdx.x;  // 64 threads = 1 wave
  int pre = train[0] ? 12000 : 6000;
  int Cb = g_cnt[b]; if (Cb > CAP) Cb = CAP;
  int Kb = min(pre, Cb);

  __shared__ float kx1[POSTMAX], ky1[POSTMAX], kx2[POSTMAX], ky2[POSTMAX], kar[POSTMAX];
  int nk = 0;

  float4 bx = (Kb > 0) ? g_sbox[b][0] : make_float4(0,0,0,0);
  for (int j = 0; j < Kb; ++j) {
    float4 nxt = (j + 1 < Kb) ? g_sbox[b][j + 1] : make_float4(0,0,0,0);  // prefetch
    float area = (bx.z - bx.x + 1.0f) * (bx.w - bx.y + 1.0f);
    int flag = 0;
    for (int t = lane; t < nk; t += 64) {
      float iw = fminf(kx2[t], bx.z) - fmaxf(kx1[t], bx.x) + 1.0f;
      iw = fmaxf(iw, 0.0f);
      float ih = fminf(ky2[t], bx.w) - fmaxf(ky1[t], bx.y) + 1.0f;
      ih = fmaxf(ih, 0.0f);
      float inter = iw * ih;
      float iou = inter / (kar[t] + area - inter);
      if (iou > 0.7f) flag = 1;
    }
    if (!__any(flag)) {
      if (lane == 0) {
        kx1[nk] = bx.x; ky1[nk] = bx.y; kx2[nk] = bx.z; ky2[nk] = bx.w; kar[nk] = area;
        float* o = out + ((size_t)b * post + nk) * 5;
        o[0] = (float)b; o[1] = bx.x; o[2] = bx.y; o[3] = bx.z; o[4] = bx.w;
      }
      nk++;
      __syncthreads();
      if (nk >= post) break;
    }
    bx = nxt;
  }
  // pad remaining rows with [b,0,0,0,0]
  for (int r = nk + lane; r < post; r += 64) {
    float* o = out + ((size_t)b * post + r) * 5;
    o[0] = (float)b; o[1] = 0.0f; o[2] = 0.0f; o[3] = 0.0f; o[4] = 0.0f;
  }
}

extern "C" void kernel_launch(void* const* d_in, const int* in_sizes, int n_in,
                              void* d_out, int out_size, void* d_ws, size_t ws_size,
                              hipStream_t stream) {
  const float* cls   = (const float*)d_in[0];
  const float* dlt   = (const float*)d_in[1];
  const float* ish   = (const float*)d_in[2];
  const int*   train = (const int*)d_in[3];
  float* out = (float*)d_out;

  int post = out_size / (NB * 5);  // 300 for TEST

  k_init<<<(NB*NBUCK + 255)/256, 256, 0, stream>>>();

  dim3 gdec(NPC / 256, NB);
  k_decode<<<gdec, 256, 0, stream>>>(cls, dlt, ish);

  k_pivot<<<NB, 256, 0, stream>>>(train);

  k_compact<<<gdec, 256, 0, stream>>>();

  dim3 grank(CAP / 256, NB);
  k_rank<<<grank, 256, 0, stream>>>(train);

  k_nms<<<NB, 64, 0, stream>>>(out, train, post);
}

// Round 2
// 375.250 us; speedup vs baseline: 1.3804x; 1.3804x over previous
//
#include <hip/hip_runtime.h>

// ProposalLayer for Faster R-CNN RPN on MI355X.
// B=4, H=64, W=96, A=9 anchors, N=55296 anchors/image.
// TEST cfg: pre=6000, post=300, thresh=0.7, min_size=16.

#define NB 4
#define AH 64
#define AW 96
#define NA 9
#define NPC (AH*AW*NA)      // 55296
#define CAP 16384           // candidate buffer per image
#define PREMAX 12000        // max 'pre' (TRAIN)
#define POSTMAX 2048        // max 'post' (TRAIN)
#define NBUCK 4096
#define RTILE 2048          // rank LDS tile (u64 -> 16KB)

// anchors from _generate_anchors(16, (0.5,1,2), (8,16,32)) — verified vs numpy
__constant__ float c_anchors[NA][4] = {
  { -84.f,  -40.f,  99.f,  55.f},
  {-176.f,  -88.f, 191.f, 103.f},
  {-360.f, -184.f, 375.f, 199.f},
  { -56.f,  -56.f,  71.f,  71.f},
  {-120.f, -120.f, 135.f, 135.f},
  {-248.f, -248.f, 263.f, 263.f},
  { -36.f,  -80.f,  51.f,  95.f},
  { -80.f, -168.f,  95.f, 183.f},
  {-168.f, -344.f, 183.f, 359.f},
};

// static scratch; rewritten deterministically each call
__device__ unsigned int          g_keys[NB][NPC];
__device__ float4                g_boxes[NB][NPC];
__device__ unsigned int          g_hist[NB][NBUCK];
__device__ unsigned int          g_pivot[NB];
__device__ int                   g_cnt[NB];
__device__ unsigned long long    g_cand[NB][CAP];
__device__ float4                g_sbox[NB][PREMAX];

__global__ void k_init() {
  int t = blockIdx.x * blockDim.x + threadIdx.x;
  if (t < NB * NBUCK) ((unsigned int*)g_hist)[t] = 0u;
  if (t < NB) g_cnt[t] = 0;
}

__global__ void k_decode(const float* __restrict__ cls,
                         const float* __restrict__ dlt,
                         const float* __restrict__ ish) {
#pragma clang fp contract(off)
  int b = blockIdx.y;
  int i = blockIdx.x * blockDim.x + threadIdx.x;
  __shared__ unsigned int lh[NBUCK];
  for (int t = threadIdx.x; t < NBUCK; t += blockDim.x) lh[t] = 0u;
  __syncthreads();

  if (i < NPC) {
    int a   = i % NA;
    int pos = i / NA;
    int wx  = pos % AW;
    int hy  = pos / AW;

    float score = cls[((b * (2*NA) + NA + a) * AH + hy) * AW + wx];
    int dbase = ((b * (4*NA) + a*4) * AH + hy) * AW + wx;
    const int hw = AH * AW;
    float d0 = dlt[dbase];
    float d1 = dlt[dbase + hw];
    float d2 = dlt[dbase + 2*hw];
    float d3 = dlt[dbase + 3*hw];

    float shx = (float)(wx * 16);
    float shy = (float)(hy * 16);
    float ax1 = c_anchors[a][0] + shx;
    float ay1 = c_anchors[a][1] + shy;
    float ax2 = c_anchors[a][2] + shx;
    float ay2 = c_anchors[a][3] + shy;

    float aw_ = ax2 - ax1 + 1.0f;
    float ah_ = ay2 - ay1 + 1.0f;
    float acx = ax1 + 0.5f * aw_;
    float acy = ay1 + 0.5f * ah_;

    float pcx = d0 * aw_ + acx;
    float pcy = d1 * ah_ + acy;
    float pw  = expf(d2) * aw_;
    float ph  = expf(d3) * ah_;

    float x1 = pcx - 0.5f * pw;
    float y1 = pcy - 0.5f * ph;
    float x2 = pcx + 0.5f * pw;
    float y2 = pcy + 0.5f * ph;

    float imh = ish[b*2 + 0];
    float imw = ish[b*2 + 1];
    x1 = fminf(fmaxf(x1, 0.0f), imw - 1.0f);
    x2 = fminf(fmaxf(x2, 0.0f), imw - 1.0f);
    y1 = fminf(fmaxf(y1, 0.0f), imh - 1.0f);
    y2 = fminf(fmaxf(y2, 0.0f), imh - 1.0f);

    bool valid = ((x2 - x1 + 1.0f) >= 16.0f) && ((y2 - y1 + 1.0f) >= 16.0f);

    g_boxes[b][i] = make_float4(x1, y1, x2, y2);

    unsigned int key = 0u;
    if (valid) {
      unsigned int ub = __float_as_uint(score);
      key = (ub >> 31) ? ~ub : (ub | 0x80000000u);  // monotonic flip; valid keys >= 0x00800000
    }
    g_keys[b][i] = key;
    atomicAdd(&lh[key >> 20], 1u);
  }
  __syncthreads();
  for (int t = threadIdx.x; t < NBUCK; t += blockDim.x)
    if (lh[t]) atomicAdd(&g_hist[b][t], lh[t]);
}

// per-image two-level pivot: coarse bucket P (key>>20), then refine with
// next 12 bits so candidate count ~= pre + epsilon.
__global__ void k_pivot(const int* __restrict__ train) {
  int b = blockIdx.x;
  int tid = threadIdx.x;  // 256
  unsigned int pre = train[0] ? 12000u : 6000u;
  __shared__ unsigned int h[NBUCK];
  __shared__ unsigned int csum[256];
  __shared__ unsigned int csuf[257];
  __shared__ int sBest;
  __shared__ unsigned int sHi;

  for (int t = tid; t < NBUCK; t += 256) h[t] = g_hist[b][t];
  if (tid == 0) { sBest = 0; sHi = 0u; }
  __syncthreads();

  // ---- phase 1: coarse pivot P = largest q>=1 with suffix(q) >= pre
  unsigned int s = 0;
  for (int q = 0; q < 16; ++q) s += h[tid*16 + q];
  csum[tid] = s;
  __syncthreads();
  if (tid == 0) {
    unsigned int run = 0;
    csuf[256] = 0;
    for (int c = 255; c >= 0; --c) { run += csum[c]; csuf[c] = run; }
  }
  __syncthreads();
  {
    unsigned int run = csuf[tid + 1];
    int loc = 0;
    for (int q = tid*16 + 15; q >= tid*16; --q) {
      run += h[q];
      if (run >= pre && q >= 1) { loc = q; break; }
    }
    if (loc) atomicMax(&sBest, loc);
  }
  __syncthreads();
  int P = sBest;
  if (P == 0) {                       // fewer than pre valid candidates total
    if (tid == 0) g_pivot[b] = 1u << 20;
    return;
  }

  // ---- sHi = suffix(P+1) (count strictly above bucket P)
  {
    unsigned int part = 0;
    for (int q = tid; q < NBUCK; q += 256) if (q > P) part += h[q];
    atomicAdd(&sHi, part);
  }
  __syncthreads();
  unsigned int pre2 = pre - sHi;      // >= 1 by construction of P
  __syncthreads();

  // ---- phase 2: sub-histogram of bits 19..8 within bucket P (reuse h)
  for (int t = tid; t < NBUCK; t += 256) h[t] = 0u;
  if (tid == 0) sBest = -1;
  __syncthreads();
  for (int i = tid; i < NPC; i += 256) {
    unsigned int key = g_keys[b][i];
    if ((key >> 20) == (unsigned int)P) atomicAdd(&h[(key >> 8) & 0xFFFu], 1u);
  }
  __syncthreads();

  s = 0;
  for (int q = 0; q < 16; ++q) s += h[tid*16 + q];
  csum[tid] = s;
  __syncthreads();
  if (tid == 0) {
    unsigned int run = 0;
    csuf[256] = 0;
    for (int c = 255; c >= 0; --c) { run += csum[c]; csuf[c] = run; }
  }
  __syncthreads();
  {
    unsigned int run = csuf[tid + 1];
    int loc = -1;
    for (int q = tid*16 + 15; q >= tid*16; --q) {
      run += h[q];
      if (run >= pre2) { loc = q; break; }   // largest Q with subsuffix(Q) >= pre2
    }
    if (loc >= 0) atomicMax(&sBest, loc);
  }
  __syncthreads();
  if (tid == 0) {
    int Q = sBest; if (Q < 0) Q = 0;
    g_pivot[b] = (((unsigned int)P) << 20) | (((unsigned int)Q) << 8);
  }
}

__global__ void k_compact() {
  int b = blockIdx.y;
  int i = blockIdx.x * blockDim.x + threadIdx.x;
  if (i >= NPC) return;
  unsigned int key = g_keys[b][i];
  if (key != 0u && key >= g_pivot[b]) {
    int pos = atomicAdd(&g_cnt[b], 1);
    if (pos < CAP)
      g_cand[b][pos] = ((unsigned long long)key << 32) |
                       (unsigned long long)(0xFFFFFFFFu - (unsigned int)i);
  }
}

// exact rank (descending key, ascending index) via LDS-tiled broadcast compare
__global__ void k_rank(const int* __restrict__ train) {
  int b = blockIdx.y;
  int pre = train[0] ? 12000 : 6000;
  int Cb = g_cnt[b]; if (Cb > CAP) Cb = CAP;
  if ((int)(blockIdx.x * blockDim.x) >= Cb) return;   // uniform early-out
  int j = blockIdx.x * blockDim.x + threadIdx.x;

  __shared__ unsigned long long tl[RTILE];
  unsigned long long cj = (j < Cb) ? g_cand[b][j] : ~0ull;
  int rank = 0;
  for (int base = 0; base < Cb; base += RTILE) {
    int n = min(RTILE, Cb - base);
    for (int t = threadIdx.x; t < n; t += 256)
      tl[t] = g_cand[b][base + t];
    __syncthreads();
    int k = 0;
#pragma unroll 8
    for (; k + 8 <= n; k += 8) {
      rank += (tl[k]   > cj) + (tl[k+1] > cj) + (tl[k+2] > cj) + (tl[k+3] > cj)
            + (tl[k+4] > cj) + (tl[k+5] > cj) + (tl[k+6] > cj) + (tl[k+7] > cj);
    }
    for (; k < n; ++k) rank += (tl[k] > cj);
    __syncthreads();
  }
  if (j < Cb && rank < pre) {
    unsigned int idx = 0xFFFFFFFFu - (unsigned int)(cj & 0xFFFFFFFFull);
    g_sbox[b][rank] = g_boxes[b][idx];
  }
}

// one wave per image: batched greedy NMS, 64 candidates per step.
// Exact-equivalent to the serial scan: intra-chunk conflicts resolved via
// per-lane "conflicts with earlier candidate" bitmasks + ballot loop.
__global__ void k_nms(float* __restrict__ out, const int* __restrict__ train, int post) {
#pragma clang fp contract(off)
  int b = blockIdx.x;
  int lane = threadIdx.x;  // 64 threads = 1 wave
  int pre = train[0] ? 12000 : 6000;
  int Cb = g_cnt[b]; if (Cb > CAP) Cb = CAP;
  int Kb = min(pre, Cb);

  __shared__ float4 kbox[POSTMAX];
  __shared__ float  kar [POSTMAX];
  __shared__ float4 cbox[64];
  int nk = 0;

  unsigned long long laneBitsBelow = (lane == 0) ? 0ull : (~0ull >> (64 - lane));

  for (int base = 0; base < Kb && nk < post; base += 64) {
    int c = base + lane;
    bool active = (c < Kb);
    // degenerate box (0,0,-1,-1): zero area, zero intersection, IoU=0 — inert
    float4 bx = active ? g_sbox[b][c] : make_float4(0.f, 0.f, -1.f, -1.f);
    float area = (bx.z - bx.x + 1.0f) * (bx.w - bx.y + 1.0f);
    cbox[lane] = bx;
    __syncthreads();

    // suppression vs already-kept boxes (broadcast LDS reads)
    int supp = active ? 0 : 1;
    for (int t = 0; t < nk; ++t) {
      float4 kb = kbox[t];
      float iw = fminf(kb.z, bx.z) - fmaxf(kb.x, bx.x) + 1.0f; iw = fmaxf(iw, 0.0f);
      float ih = fminf(kb.w, bx.w) - fmaxf(kb.y, bx.y) + 1.0f; ih = fmaxf(ih, 0.0f);
      float inter = iw * ih;
      float iou = inter / (kar[t] + area - inter);
      supp |= (iou > 0.7f);
    }

    // intra-chunk pairwise conflict bits (only j < lane matter)
    unsigned long long conf = 0ull;
    for (int j = 0; j < 64; ++j) {
      float4 ob = cbox[j];
      float oarea = (ob.z - ob.x + 1.0f) * (ob.w - ob.y + 1.0f);
      float iw = fminf(ob.z, bx.z) - fmaxf(ob.x, bx.x) + 1.0f; iw = fmaxf(iw, 0.0f);
      float ih = fminf(ob.w, bx.w) - fmaxf(ob.y, bx.y) + 1.0f; ih = fmaxf(ih, 0.0f);
      float inter = iw * ih;
      float iou = inter / (oarea + area - inter);
      if (iou > 0.7f) conf |= (1ull << j);
    }
    conf &= laneBitsBelow;

    // serial resolve: keep lowest pending index, drop its conflicts
    unsigned long long pending = __ballot(!supp);
    unsigned long long keptmask = 0ull;
    while (pending) {
      int i = __ffsll((unsigned long long)pending) - 1;
      keptmask |= (1ull << i);
      unsigned long long confb = __ballot((int)((conf >> i) & 1ull));
      pending &= ~confb;
      pending &= ~(1ull << i);
    }

    // append keeps in order; write output rows
    int myPos = nk + __popcll(keptmask & laneBitsBelow);
    if (((keptmask >> lane) & 1ull) && myPos < post) {
      kbox[myPos] = bx;
      kar [myPos] = area;
      float* o = out + ((size_t)b * post + myPos) * 5;
      o[0] = (float)b; o[1] = bx.x; o[2] = bx.y; o[3] = bx.z; o[4] = bx.w;
    }
    nk += __popcll(keptmask);
    __syncthreads();
    if (nk >= post) break;
  }

  nk = min(nk, post);
  for (int r = nk + lane; r < post; r += 64) {
    float* o = out + ((size_t)b * post + r) * 5;
    o[0] = (float)b; o[1] = 0.0f; o[2] = 0.0f; o[3] = 0.0f; o[4] = 0.0f;
  }
}

extern "C" void kernel_launch(void* const* d_in, const int* in_sizes, int n_in,
                              void* d_out, int out_size, void* d_ws, size_t ws_size,
                              hipStream_t stream) {
  const float* cls   = (const float*)d_in[0];
  const float* dlt   = (const float*)d_in[1];
  const float* ish   = (const float*)d_in[2];
  const int*   train = (const int*)d_in[3];
  float* out = (float*)d_out;

  int post = out_size / (NB * 5);  // 300 for TEST

  k_init<<<(NB*NBUCK + 255)/256, 256, 0, stream>>>();

  dim3 gdec(NPC / 256, NB);
  k_decode<<<gdec, 256, 0, stream>>>(cls, dlt, ish);

  k_pivot<<<NB, 256, 0, stream>>>(train);

  k_compact<<<gdec, 256, 0, stream>>>();

  dim3 grank(CAP / 256, NB);
  k_rank<<<grank, 256, 0, stream>>>(train);

  k_nms<<<NB, 64, 0, stream>>>(out, train, post);
}